// Round 1
// baseline (1050.108 us; speedup 1.0000x reference)
//
#include <hip/hip_runtime.h>
#include <hip/hip_bf16.h>

typedef __hip_bfloat16 bf16;
typedef __attribute__((ext_vector_type(8))) short s8v;
typedef __attribute__((ext_vector_type(4))) float f4;

#define DEVI __device__ __forceinline__

DEVI f4 mfma16(s8v a, s8v b, f4 c){
  return __builtin_amdgcn_mfma_f32_16x16x32_bf16(a, b, c, 0, 0, 0);
}

constexpr int NPIX = 65536;   // 256*256
constexpr int NDOWN = 1024;   // 32*32

// ---------------- cast weights to bf16 ----------------
// layout in wbf (elements): [0) w_conv1 73728 | [73728) w_conv4a 36864 |
//                           [110592) w_proj 73728 | [184320) w_qkv 110592
__global__ void k_cast_w(const float* __restrict__ w1, const float* __restrict__ w4a,
                         const float* __restrict__ wp, const float* __restrict__ wq,
                         bf16* __restrict__ out){
  int i = blockIdx.x*256 + threadIdx.x;
  if (i < 73728) out[i] = __float2bfloat16(w1[i]);
  else if (i < 110592) out[i] = __float2bfloat16(w4a[i - 73728]);
  else if (i < 184320) out[i] = __float2bfloat16(wp[i - 110592]);
  else if (i < 294912) out[i] = __float2bfloat16(wq[i - 184320]);
}

// ---------------- pack x: fp32 planar -> bf16 K-packed [b][24][65536][8] ----------------
__global__ void k_pack_x(const float* __restrict__ x, bf16* __restrict__ xp){
  __shared__ float t[8][1032];
  int b = blockIdx.z, cb = blockIdx.y, ns = blockIdx.x, tid = threadIdx.x;
  const float* src = x + ((size_t)(b*192 + cb*8))*NPIX + ns*1024;
  #pragma unroll
  for (int i = 0; i < 8; ++i){
    float4 v = *(const float4*)(src + (size_t)i*NPIX + tid*4);
    *(float4*)&t[i][tid*4] = v;
  }
  __syncthreads();
  bf16* dst = xp + (((size_t)(b*24 + cb))*NPIX + ns*1024)*8;
  #pragma unroll
  for (int j = 0; j < 4; ++j){
    int p = j*256 + tid;
    alignas(16) bf16 c8[8];
    #pragma unroll
    for (int i = 0; i < 8; ++i) c8[i] = __float2bfloat16(t[i][p]);
    *(uint4*)(dst + (size_t)p*8) = *(const uint4*)c8;
  }
}

// ---------------- avg-pool 8x8 -> packed bf16 [b][24][1024][8] ----------------
__global__ void k_pool(const bf16* __restrict__ xp, bf16* __restrict__ xdp){
  __shared__ float red[8][32][8];
  int b = blockIdx.z, cb = blockIdx.y, hd = blockIdx.x, tid = threadIdx.x;
  int r = tid >> 5, wd = tid & 31;
  const bf16* src = xp + (((size_t)(b*24 + cb))*NPIX + (hd*8 + r)*256 + wd*8)*8;
  float acc[8] = {0,0,0,0,0,0,0,0};
  #pragma unroll
  for (int ww = 0; ww < 8; ++ww){
    uint4 raw = *(const uint4*)(src + ww*8);
    const bf16* c8 = (const bf16*)&raw;
    #pragma unroll
    for (int i = 0; i < 8; ++i) acc[i] += __bfloat162float(c8[i]);
  }
  #pragma unroll
  for (int i = 0; i < 8; ++i) red[r][wd][i] = acc[i];
  __syncthreads();
  if (tid < 32){
    alignas(16) bf16 o8[8];
    #pragma unroll
    for (int i = 0; i < 8; ++i){
      float s = 0.f;
      #pragma unroll
      for (int rr = 0; rr < 8; ++rr) s += red[rr][tid][i];
      o8[i] = __float2bfloat16(s * (1.0f/64.0f));
    }
    *(uint4*)(xdp + (((size_t)(b*24 + cb))*NDOWN + hd*32 + tid)*8) = *(const uint4*)o8;
  }
}

// ---------------- MFMA GEMM: out[b][m][n] = sum_k W[m][k] * Bp[b][k][n] ----------------
// Bp is K-packed bf16 [b][K/8][npix][8]. Block tile 96(M) x 128(N), 4 waves of 48x64.
// PLANAR=false: packed bf16 out [b][outkb][npix][8]; PLANAR=true: planar fp32, outkb=#channels.
template<int K, bool PLANAR>
__launch_bounds__(256, 2)
__global__ void k_gemm(const bf16* __restrict__ Bp, const bf16* __restrict__ W,
                       void* __restrict__ outp, int npix, int outkb){
  constexpr int KB8 = K/8;
  constexpr int NIT = K/64;
  __shared__ bf16 As[96*72];
  __shared__ bf16 Bs[128*72];
  int tid = threadIdx.x;
  int b = blockIdx.z;
  int m0 = blockIdx.y*96;
  int n0 = blockIdx.x*128;
  int wave = tid >> 6, lane = tid & 63;
  int wm = wave >> 1, wn = wave & 1;
  int lr = lane & 15, kg = lane >> 4;
  f4 acc[3][4] = {};
  const size_t bK = (size_t)b * KB8;
  for (int kt = 0; kt < NIT; ++kt){
    {
      int idx = tid;
      #pragma unroll
      for (int j = 0; j < 3; ++j, idx += 256){
        int m = idx >> 3, kc = idx & 7;
        *(uint4*)&As[m*72 + kc*8] = *(const uint4*)(W + (size_t)(m0 + m)*K + kt*64 + kc*8);
      }
      idx = tid;
      #pragma unroll
      for (int j = 0; j < 4; ++j, idx += 256){
        int kb = idx >> 7, n = idx & 127;
        *(uint4*)&Bs[n*72 + kb*8] = *(const uint4*)(Bp + ((bK + kt*8 + kb)*npix + n0 + n)*8);
      }
    }
    __syncthreads();
    #pragma unroll
    for (int kk = 0; kk < 2; ++kk){
      s8v af[3]; s8v bfr[4];
      int ko = kk*32 + kg*8;
      #pragma unroll
      for (int mf = 0; mf < 3; ++mf) af[mf] = *(const s8v*)&As[(wm*48 + mf*16 + lr)*72 + ko];
      #pragma unroll
      for (int nf = 0; nf < 4; ++nf) bfr[nf] = *(const s8v*)&Bs[(wn*64 + nf*16 + lr)*72 + ko];
      #pragma unroll
      for (int mf = 0; mf < 3; ++mf)
        #pragma unroll
        for (int nf = 0; nf < 4; ++nf)
          acc[mf][nf] = mfma16(af[mf], bfr[nf], acc[mf][nf]);
    }
    __syncthreads();
  }
  int quad = lane >> 4;
  #pragma unroll
  for (int mf = 0; mf < 3; ++mf){
    int mb = m0 + wm*48 + mf*16 + quad*4;
    #pragma unroll
    for (int nf = 0; nf < 4; ++nf){
      int n = n0 + wn*64 + nf*16 + lr;
      if constexpr (PLANAR){
        float* o = (float*)outp;
        #pragma unroll
        for (int r2 = 0; r2 < 4; ++r2)
          o[((size_t)(b*outkb + mb + r2))*npix + n] = acc[mf][nf][r2];
      } else {
        bf16* o = (bf16*)outp;
        alignas(8) bf16 v4[4];
        #pragma unroll
        for (int r2 = 0; r2 < 4; ++r2) v4[r2] = __float2bfloat16(acc[mf][nf][r2]);
        *(uint2*)(o + ((size_t)(b*outkb + (mb >> 3))*npix + n)*8 + (mb & 7)) = *(const uint2*)v4;
      }
    }
  }
}

// ---------------- high branch: strip dw convs + 3x3 dw, fused ----------------
// xp packed [b][24][65536][8] -> hw3p packed [b][48][65536][8]
// kblk 0..23 = 3x3dw(dww branch), kblk 24..47 = 3x3dw(dwh branch)
__global__ void k_high_dw(const bf16* __restrict__ xp,
    const float* __restrict__ wdww, const float* __restrict__ bdww,
    const float* __restrict__ wdwh, const float* __restrict__ bdwh,
    const float* __restrict__ w3, const float* __restrict__ b3,
    bf16* __restrict__ hw3p){
  __shared__ bf16 xs[28*28*8];
  __shared__ float dwwt[18*18*8];
  __shared__ float dwht[18*18*8];
  int t = blockIdx.x, cb = blockIdx.y, b = blockIdx.z, tid = threadIdx.x;
  int r0 = (t >> 4)*16, c0 = (t & 15)*16;
  const bf16* src = xp + ((size_t)(b*24 + cb))*NPIX*8;
  for (int i = tid; i < 784; i += 256){
    int r = i/28, c = i - r*28;
    int gr = r0 + r - 6, gc = c0 + c - 6;
    uint4 v = {0,0,0,0};
    if ((unsigned)gr < 256u && (unsigned)gc < 256u)
      v = *(const uint4*)(src + ((size_t)(gr*256 + gc))*8);
    *(uint4*)&xs[i*8] = v;
  }
  __syncthreads();
  {
    int ch = tid & 7, pr = tid >> 3;
    int cg = cb*8 + ch;
    float ww[11], wh[11];
    #pragma unroll
    for (int j = 0; j < 11; ++j){ ww[j] = wdww[cg*11 + j]; wh[j] = wdwh[cg*11 + j]; }
    float bw = bdww[cg], bh = bdwh[cg];
    for (int p = pr; p < 324; p += 32){
      int r = p/18, c = p - r*18;
      int gr = r0 + r - 1, gc = c0 + c - 1;
      float vww = 0.f, vwh = 0.f;
      if ((unsigned)gr < 256u && (unsigned)gc < 256u){
        vww = bw; vwh = bh;
        #pragma unroll
        for (int j = 0; j < 11; ++j){
          vww += ww[j]*__bfloat162float(xs[((r+5)*28 + c + j)*8 + ch]);
          vwh += wh[j]*__bfloat162float(xs[((r+j)*28 + c + 5)*8 + ch]);
        }
      }
      dwwt[p*8 + ch] = vww;
      dwht[p*8 + ch] = vwh;
    }
  }
  __syncthreads();
  {
    int r = tid >> 4, c = tid & 15;
    int n = (r0 + r)*256 + c0 + c;
    alignas(16) bf16 o1[8], o2[8];
    #pragma unroll
    for (int ch = 0; ch < 8; ++ch){
      int cg = cb*8 + ch;
      float s1 = b3[cg], s2 = b3[192 + cg];
      #pragma unroll
      for (int dr = 0; dr < 3; ++dr)
        #pragma unroll
        for (int dc = 0; dc < 3; ++dc){
          int pi = ((r + dr)*18 + c + dc)*8 + ch;
          s1 += w3[cg*9 + dr*3 + dc]         * dwwt[pi];
          s2 += w3[(192 + cg)*9 + dr*3 + dc] * dwht[pi];
        }
      o1[ch] = __float2bfloat16(s1);
      o2[ch] = __float2bfloat16(s2);
    }
    *(uint4*)(hw3p + (((size_t)(b*48 + cb))*NPIX + n)*8)      = *(const uint4*)o1;
    *(uint4*)(hw3p + (((size_t)(b*48 + 24 + cb))*NPIX + n)*8) = *(const uint4*)o2;
  }
}

// ---------------- qkv depthwise 3x3 (+ v max/avg reduction for cb>=48) ----------------
__global__ void k_qkv_dw(const bf16* __restrict__ qkv0p, const float* __restrict__ wdw,
                         float* __restrict__ qkvd, float* __restrict__ vmax, float* __restrict__ vavg){
  __shared__ bf16 xs[34*34*8];
  __shared__ float red[256*8];
  int cb = blockIdx.x, b = blockIdx.y, tid = threadIdx.x;
  for (int i = tid; i < 1156; i += 256){
    int r = i/34, c = i - r*34;
    int gr = r - 1, gc = c - 1;
    uint4 v = {0,0,0,0};
    if ((unsigned)gr < 32u && (unsigned)gc < 32u)
      v = *(const uint4*)(qkv0p + (((size_t)(b*72 + cb))*NDOWN + gr*32 + gc)*8);
    *(uint4*)&xs[i*8] = v;
  }
  __syncthreads();
  float mxv[8], smv[8];
  #pragma unroll
  for (int ch = 0; ch < 8; ++ch){ mxv[ch] = -3.4e38f; smv[ch] = 0.f; }
  for (int j = 0; j < 4; ++j){
    int p = j*256 + tid;
    int r = p >> 5, c = p & 31;
    #pragma unroll
    for (int ch = 0; ch < 8; ++ch){
      float s = 0.f;
      #pragma unroll
      for (int dr = 0; dr < 3; ++dr)
        #pragma unroll
        for (int dc = 0; dc < 3; ++dc)
          s += wdw[(cb*8 + ch)*9 + dr*3 + dc] *
               __bfloat162float(xs[((r + dr)*34 + c + dc)*8 + ch]);
      qkvd[((size_t)(b*576 + cb*8 + ch))*NDOWN + p] = s;
      mxv[ch] = fmaxf(mxv[ch], s);
      smv[ch] += s;
    }
  }
  if (cb >= 48){
    #pragma unroll
    for (int ch = 0; ch < 8; ++ch) red[tid*8 + ch] = mxv[ch];
    __syncthreads();
    for (int st = 128; st > 0; st >>= 1){
      if (tid < st)
        #pragma unroll
        for (int ch = 0; ch < 8; ++ch)
          red[tid*8 + ch] = fmaxf(red[tid*8 + ch], red[(tid + st)*8 + ch]);
      __syncthreads();
    }
    if (tid < 8) vmax[b*192 + (cb - 48)*8 + tid] = red[tid];
    __syncthreads();
    #pragma unroll
    for (int ch = 0; ch < 8; ++ch) red[tid*8 + ch] = smv[ch];
    __syncthreads();
    for (int st = 128; st > 0; st >>= 1){
      if (tid < st)
        #pragma unroll
        for (int ch = 0; ch < 8; ++ch) red[tid*8 + ch] += red[(tid + st)*8 + ch];
      __syncthreads();
    }
    if (tid < 8) vavg[b*192 + (cb - 48)*8 + tid] = red[tid] * (1.0f/1024.0f);
  }
}

// ---------------- attention matrix: normalize q,k rows; softmax(temp * q_hat k_hat^T) ----------------
__global__ void k_attn(const float* __restrict__ qkvd, const float* __restrict__ temp,
                       float* __restrict__ attn){
  __shared__ float inv[48];
  __shared__ float sm[576];
  int bh = blockIdx.x;
  int b = bh >> 3, h = bh & 7;
  const float* qb = qkvd + ((size_t)(b*576 + h*24))*NDOWN;
  const float* kb = qkvd + ((size_t)(b*576 + 192 + h*24))*NDOWN;
  int tid = threadIdx.x, wave = tid >> 6, lane = tid & 63;
  for (int v = wave; v < 48; v += 4){
    const float* p = (v < 24) ? (qb + v*NDOWN) : (kb + (v - 24)*NDOWN);
    float s = 0.f;
    for (int i = lane; i < NDOWN; i += 64){ float xv = p[i]; s += xv*xv; }
    #pragma unroll
    for (int o = 32; o > 0; o >>= 1) s += __shfl_down(s, o);
    if (lane == 0) inv[v] = 1.0f / fmaxf(sqrtf(s), 1e-12f);
  }
  __syncthreads();
  float tp = temp[h];
  for (int pr = tid; pr < 576; pr += 256){
    int c = pr/24, d = pr - c*24;
    const float4* qp = (const float4*)(qb + c*NDOWN);
    const float4* kp = (const float4*)(kb + d*NDOWN);
    float s = 0.f;
    for (int i = 0; i < 256; ++i){
      float4 a = qp[i], e = kp[i];
      s += a.x*e.x + a.y*e.y + a.z*e.z + a.w*e.w;
    }
    sm[pr] = s * inv[c] * inv[24 + d] * tp;
  }
  __syncthreads();
  if (tid < 24){
    float mx = -3.4e38f;
    for (int d = 0; d < 24; ++d) mx = fmaxf(mx, sm[tid*24 + d]);
    float sum = 0.f;
    for (int d = 0; d < 24; ++d) sum += __expf(sm[tid*24 + d] - mx);
    float isum = 1.0f / sum;
    for (int d = 0; d < 24; ++d)
      attn[((size_t)bh)*576 + tid*24 + d] = __expf(sm[tid*24 + d] - mx) * isum;
  }
}

// ---------------- gate: W2 @ vmax + W3 @ vavg ----------------
__global__ void k_gate(const float* __restrict__ vmax, const float* __restrict__ vavg,
                       const float* __restrict__ w2, const float* __restrict__ w3,
                       float* __restrict__ gate){
  __shared__ float vm[192], va[192];
  int b = blockIdx.x, tid = threadIdx.x;
  if (tid < 192){ vm[tid] = vmax[b*192 + tid]; va[tid] = vavg[b*192 + tid]; }
  __syncthreads();
  if (tid < 192){
    float s = 0.f;
    const float* w2r = w2 + tid*192;
    const float* w3r = w3 + tid*192;
    for (int k = 0; k < 192; ++k) s += w2r[k]*vm[k] + w3r[k]*va[k];
    gate[b*192 + tid] = s;
  }
}

// ---------------- low branch: conv4b dw 3x3 + gate + per-head 24x24 attn apply ----------------
__global__ void k_low(const bf16* __restrict__ x4ap, const float* __restrict__ attn,
                      const float* __restrict__ gate, const float* __restrict__ w4b,
                      bf16* __restrict__ hlp){
  __shared__ bf16 xt[3*18*18*8];
  __shared__ float a2[576];
  __shared__ float wt[216];
  __shared__ float vt[24*256];
  int t = blockIdx.x, h = blockIdx.y, b = blockIdx.z, tid = threadIdx.x;
  int r0 = (t >> 4)*16, c0 = (t & 15)*16;
  int ch0 = h*24;
  for (int i = tid; i < 576; i += 256)
    a2[i] = attn[((size_t)(b*8 + h))*576 + i] * gate[b*192 + ch0 + (i % 24)];
  for (int i = tid; i < 216; i += 256) wt[i] = w4b[ch0*9 + i];
  for (int i = tid; i < 972; i += 256){
    int kb = i/324, p = i - kb*324;
    int r = p/18, c = p - r*18;
    int gr = r0 + r - 1, gc = c0 + c - 1;
    uint4 v = {0,0,0,0};
    if ((unsigned)gr < 256u && (unsigned)gc < 256u)
      v = *(const uint4*)(x4ap + (((size_t)(b*24 + h*3 + kb))*NPIX + gr*256 + gc)*8);
    *(uint4*)&xt[i*8] = v;
  }
  __syncthreads();
  {
    int r = tid >> 4, c = tid & 15;
    #pragma unroll
    for (int ch = 0; ch < 24; ++ch){
      int kb = ch >> 3, ci = ch & 7;
      float s = 0.f;
      #pragma unroll
      for (int dr = 0; dr < 3; ++dr)
        #pragma unroll
        for (int dc = 0; dc < 3; ++dc)
          s += wt[ch*9 + dr*3 + dc] *
               __bfloat162float(xt[((kb*18 + r + dr)*18 + c + dc)*8 + ci]);
      vt[ch*256 + tid] = s;
    }
  }
  __syncthreads();
  {
    float o[24];
    #pragma unroll
    for (int cc = 0; cc < 24; ++cc){
      float s = 0.f;
      #pragma unroll
      for (int d = 0; d < 24; ++d) s += a2[cc*24 + d] * vt[d*256 + tid];
      o[cc] = s;
    }
    int n = (r0 + (tid >> 4))*256 + c0 + (tid & 15);
    #pragma unroll
    for (int kb = 0; kb < 3; ++kb){
      alignas(16) bf16 c8[8];
      #pragma unroll
      for (int i = 0; i < 8; ++i) c8[i] = __float2bfloat16(o[kb*8 + i]);
      *(uint4*)(hlp + (((size_t)(b*48 + 24 + h*3 + kb))*NPIX + n)*8) = *(const uint4*)c8;
    }
  }
}

extern "C" void kernel_launch(void* const* d_in, const int* in_sizes, int n_in,
                              void* d_out, int out_size, void* d_ws, size_t ws_size,
                              hipStream_t stream){
  const float* x        = (const float*)d_in[0];
  const float* w_dww    = (const float*)d_in[1];
  const float* b_dww    = (const float*)d_in[2];
  const float* w_dwh    = (const float*)d_in[3];
  const float* b_dwh    = (const float*)d_in[4];
  const float* w_dwhw   = (const float*)d_in[5];
  const float* b_dwhw   = (const float*)d_in[6];
  const float* w_conv1  = (const float*)d_in[7];
  const float* w_qkv    = (const float*)d_in[8];
  const float* w_qkvdw  = (const float*)d_in[9];
  const float* w_conv2  = (const float*)d_in[10];
  const float* w_conv3  = (const float*)d_in[11];
  const float* w_conv4a = (const float*)d_in[12];
  const float* w_conv4b = (const float*)d_in[13];
  const float* w_proj   = (const float*)d_in[14];
  const float* temp     = (const float*)d_in[15];

  char* ws = (char*)d_ws;
  size_t off = 0;
  auto take = [&](size_t bytes)->char*{
    char* r = ws + off;
    off = (off + bytes + 255) & ~(size_t)255;
    return r;
  };
  bf16*  xp    = (bf16*) take((size_t)4*192*65536*2);  // packed x
  bf16*  hw3p  = (bf16*) take((size_t)4*384*65536*2);  // packed high pre-conv1
  bf16*  hlp   = (bf16*) take((size_t)4*384*65536*2);  // packed [high|low] proj input
  bf16*  x4ap  = (bf16*) take((size_t)4*192*65536*2);  // packed conv4a out
  bf16*  xdp   = (bf16*) take((size_t)4*192*1024*2);   // packed pooled x
  bf16*  qkv0p = (bf16*) take((size_t)4*576*1024*2);   // packed qkv 1x1 out
  float* qkvd  = (float*)take((size_t)4*576*1024*4);   // planar qkv post-dw
  float* attn  = (float*)take((size_t)4*8*576*4);
  float* vmax  = (float*)take((size_t)4*192*4);
  float* vavg  = (float*)take((size_t)4*192*4);
  float* gate  = (float*)take((size_t)4*192*4);
  bf16*  wbf   = (bf16*) take((size_t)294912*2);
  if (off > ws_size) return;  // workspace too small: fail loudly via absmax

  k_cast_w<<<1152, 256, 0, stream>>>(w_conv1, w_conv4a, w_proj, w_qkv, wbf);
  k_pack_x<<<dim3(64,24,4), 256, 0, stream>>>(x, xp);
  k_pool<<<dim3(32,24,4), 256, 0, stream>>>(xp, xdp);
  k_gemm<192,false><<<dim3(8,6,4), 256, 0, stream>>>(xdp, wbf + 184320, qkv0p, 1024, 72);
  k_qkv_dw<<<dim3(72,4), 256, 0, stream>>>(qkv0p, w_qkvdw, qkvd, vmax, vavg);
  k_attn<<<32, 256, 0, stream>>>(qkvd, temp, attn);
  k_gate<<<4, 192, 0, stream>>>(vmax, vavg, w_conv2, w_conv3, gate);
  k_high_dw<<<dim3(256,24,4), 256, 0, stream>>>(xp, w_dww, b_dww, w_dwh, b_dwh, w_dwhw, b_dwhw, hw3p);
  k_gemm<384,false><<<dim3(512,2,4), 256, 0, stream>>>(hw3p, wbf, hlp, 65536, 48);
  k_gemm<192,false><<<dim3(512,2,4), 256, 0, stream>>>(xp, wbf + 73728, x4ap, 65536, 24);
  k_low<<<dim3(256,8,4), 256, 0, stream>>>(x4ap, attn, gate, w_conv4b, hlp);
  k_gemm<384,true><<<dim3(512,2,4), 256, 0, stream>>>(hlp, wbf + 110592, d_out, 65536, 192);
}